// Round 9
// baseline (181.768 us; speedup 1.0000x reference)
//
#include <hip/hip_runtime.h>
#include <math.h>

typedef __bf16 bf16;
typedef __attribute__((ext_vector_type(8))) __bf16 bf16x8;
typedef __attribute__((ext_vector_type(4))) __bf16 bf16x4;
typedef __attribute__((ext_vector_type(4))) float f32x4;

typedef __attribute__((address_space(1))) unsigned int glb_u32;
typedef __attribute__((address_space(3))) unsigned int lds_u32;

#define NEGV (-4294967295.0f)
#define SCL2 0.18033688011112042f  /* 0.125 * log2(e), folded into Q */

__device__ __forceinline__ void async_cp16(const void* g, void* l) {
  __builtin_amdgcn_global_load_lds((glb_u32*)g, (lds_u32*)l, 16, 0, 0);
}

// ---- DPP 16-lane butterfly reduce (VALU pipe, not LDS) --------------------
template <int CTRL>
__device__ __forceinline__ float dppf(float x) {
  return __builtin_bit_cast(float,
      __builtin_amdgcn_mov_dpp(__builtin_bit_cast(int, x), CTRL, 0xF, 0xF, true));
}
__device__ __forceinline__ float dpp_max16(float x) {
  x = fmaxf(x, dppf<0xB1>(x));   // quad_perm xor1
  x = fmaxf(x, dppf<0x4E>(x));   // quad_perm xor2
  x = fmaxf(x, dppf<0x141>(x));  // row_half_mirror
  x = fmaxf(x, dppf<0x140>(x));  // row_mirror
  return x;
}

// ---------------- fp32 -> bf16 convert, all three inputs in one launch ----
__global__ __launch_bounds__(256) void cvt3_kernel(
    const float* __restrict__ q, const float* __restrict__ k,
    const float* __restrict__ v, short* xq, short* xk, short* xv) {
  const int bid = blockIdx.x;
  const int which = bid >> 12;           // 0..2
  const int i = (bid & 4095) * 256 + threadIdx.x;
  const float* src = which == 0 ? q : (which == 1 ? k : v);
  short* dst = which == 0 ? xq : (which == 1 ? xk : xv);
  float4 vv = ((const float4*)src)[i];
  bf16x4 o;
  o[0] = (bf16)vv.x; o[1] = (bf16)vv.y; o[2] = (bf16)vv.z; o[3] = (bf16)vv.w;
  ((bf16x4*)dst)[i] = o;
}

// ---------------- weight transpose + convert: T[n][k] = W[k][n] -----------
__global__ __launch_bounds__(256) void wt_kernel(
    const float* __restrict__ W0, const float* __restrict__ W1,
    const float* __restrict__ W2, const float* __restrict__ W3,
    short* T0, short* T1, short* T2, short* T3) {
  __shared__ float tile[64][65];
  const float* W = blockIdx.z == 0 ? W0 : (blockIdx.z == 1 ? W1 : (blockIdx.z == 2 ? W2 : W3));
  bf16* T = (bf16*)(blockIdx.z == 0 ? T0 : (blockIdx.z == 1 ? T1 : (blockIdx.z == 2 ? T2 : T3)));
  const int k0 = blockIdx.y * 64, n0 = blockIdx.x * 64;
  const int tid = threadIdx.x;
  const int c = tid & 63, rr = tid >> 6;
#pragma unroll
  for (int i = 0; i < 16; i++) {
    int r = i * 4 + rr;
    tile[r][c] = W[(size_t)(k0 + r) * 1024 + n0 + c];
  }
  __syncthreads();
#pragma unroll
  for (int i = 0; i < 16; i++) {
    int r = i * 4 + rr;
    T[(size_t)(n0 + r) * 1024 + k0 + c] = (bf16)tile[c][r];
  }
}

// ---------------- QKV projection GEMM: Y = relu(X @ W + b) ----------------
__global__ __launch_bounds__(256) void qkv_gemm(
    const short* Xq_, const short* Xk_, const short* Xv_,
    const short* Wtq_, const short* Wtk_, const short* Wtv_,
    const float* __restrict__ bq_, const float* __restrict__ bk_, const float* __restrict__ bv_,
    short* Qo_, short* Ko_, short* Vto_) {
  __shared__ bf16 Alds[128][32];
  __shared__ bf16 Blds[128][32];
  const int which = blockIdx.z;
  const bf16* X  = (const bf16*)(which == 0 ? Xq_  : (which == 1 ? Xk_  : Xv_));
  const bf16* Wt = (const bf16*)(which == 0 ? Wtq_ : (which == 1 ? Wtk_ : Wtv_));
  const float* bias = which == 0 ? bq_ : (which == 1 ? bk_ : bv_);
  const int m0 = blockIdx.y * 128, n0 = blockIdx.x * 128;
  const int tid = threadIdx.x, wid = tid >> 6, lane = tid & 63;
  const int wr = wid >> 1, wc = wid & 1;
  const int l15 = lane & 15, lg = lane >> 4;
  const f32x4 vzero = {0.f, 0.f, 0.f, 0.f};
  f32x4 acc[4][4];
#pragma unroll
  for (int m = 0; m < 4; m++)
#pragma unroll
    for (int n = 0; n < 4; n++) acc[m][n] = vzero;

  const int sr = wid * 32 + (lane >> 2);
  const int scb = (lane & 3) * 16;

  for (int kt = 0; kt < 32; ++kt) {
    const char* ga = (const char*)(X + (size_t)(m0 + sr) * 1024 + kt * 32) + scb;
    async_cp16(ga, &Alds[wid * 32][0]);
    async_cp16(ga + 16 * 2048, &Alds[wid * 32 + 16][0]);
    const char* gb = (const char*)(Wt + (size_t)(n0 + sr) * 1024 + kt * 32) + scb;
    async_cp16(gb, &Blds[wid * 32][0]);
    async_cp16(gb + 16 * 2048, &Blds[wid * 32 + 16][0]);
    __syncthreads();
    bf16x8 a[4], bb[4];
#pragma unroll
    for (int m = 0; m < 4; m++) a[m] = *(const bf16x8*)&Alds[wr * 64 + m * 16 + l15][lg * 8];
#pragma unroll
    for (int n = 0; n < 4; n++) bb[n] = *(const bf16x8*)&Blds[wc * 64 + n * 16 + l15][lg * 8];
#pragma unroll
    for (int m = 0; m < 4; m++)
#pragma unroll
      for (int n = 0; n < 4; n++)
        acc[m][n] = __builtin_amdgcn_mfma_f32_16x16x32_bf16(a[m], bb[n], acc[m][n], 0, 0, 0);
    __syncthreads();
  }

  if (which != 2) {
    bf16* Y = (bf16*)(which == 0 ? Qo_ : Ko_);
    const float osc = (which == 0) ? SCL2 : 1.0f;
#pragma unroll
    for (int n = 0; n < 4; n++) {
      const int col = n0 + wc * 64 + n * 16 + l15;
      const float bv = bias[col];
#pragma unroll
      for (int m = 0; m < 4; m++) {
        const int row0 = m0 + wr * 64 + m * 16 + lg * 4;
#pragma unroll
        for (int r = 0; r < 4; r++) {
          float v = acc[m][n][r] + bv;
          v = v > 0.f ? v : 0.f;
          Y[(size_t)(row0 + r) * 1024 + col] = (bf16)(v * osc);
        }
      }
    }
  } else {
    bf16* Vt = (bf16*)Vto_;
#pragma unroll
    for (int n = 0; n < 4; n++) {
      const int col = n0 + wc * 64 + n * 16 + l15;
      const float bv = bias[col];
#pragma unroll
      for (int m = 0; m < 4; m++) {
        const int row0 = m0 + wr * 64 + m * 16 + lg * 4;
        const int bb2 = row0 >> 11;
        const int s = row0 & 2047;
        bf16x4 pk;
#pragma unroll
        for (int r = 0; r < 4; r++) {
          float v = acc[m][n][r] + bv;
          v = v > 0.f ? v : 0.f;
          pk[r] = (bf16)v;
        }
        *(bf16x4*)(Vt + ((size_t)bb2 * 1024 + col) * 2048 + s) = pk;
      }
    }
  }
}

// ---------------- output projection GEMM (fp32 out, no transpose) ---------
__global__ __launch_bounds__(256) void out_gemm(
    const short* A_, const short* Wt_, const float* __restrict__ bias,
    float* __restrict__ Y) {
  __shared__ bf16 Alds[128][32];
  __shared__ bf16 Blds[128][32];
  const bf16* X = (const bf16*)A_;
  const bf16* Wt = (const bf16*)Wt_;
  const int m0 = blockIdx.y * 128, n0 = blockIdx.x * 128;
  const int tid = threadIdx.x, wid = tid >> 6, lane = tid & 63;
  const int wr = wid >> 1, wc = wid & 1;
  const int l15 = lane & 15, lg = lane >> 4;
  const f32x4 vzero = {0.f, 0.f, 0.f, 0.f};
  f32x4 acc[4][4];
#pragma unroll
  for (int m = 0; m < 4; m++)
#pragma unroll
    for (int n = 0; n < 4; n++) acc[m][n] = vzero;

  const int sr = wid * 32 + (lane >> 2);
  const int scb = (lane & 3) * 16;

  for (int kt = 0; kt < 32; ++kt) {
    const char* ga = (const char*)(X + (size_t)(m0 + sr) * 1024 + kt * 32) + scb;
    async_cp16(ga, &Alds[wid * 32][0]);
    async_cp16(ga + 16 * 2048, &Alds[wid * 32 + 16][0]);
    const char* gb = (const char*)(Wt + (size_t)(n0 + sr) * 1024 + kt * 32) + scb;
    async_cp16(gb, &Blds[wid * 32][0]);
    async_cp16(gb + 16 * 2048, &Blds[wid * 32 + 16][0]);
    __syncthreads();
    bf16x8 a[4], bb[4];
#pragma unroll
    for (int m = 0; m < 4; m++) a[m] = *(const bf16x8*)&Alds[wr * 64 + m * 16 + l15][lg * 8];
#pragma unroll
    for (int n = 0; n < 4; n++) bb[n] = *(const bf16x8*)&Blds[wc * 64 + n * 16 + l15][lg * 8];
#pragma unroll
    for (int m = 0; m < 4; m++)
#pragma unroll
      for (int n = 0; n < 4; n++)
        acc[m][n] = __builtin_amdgcn_mfma_f32_16x16x32_bf16(a[m], bb[n], acc[m][n], 0, 0, 0);
    __syncthreads();
  }
#pragma unroll
  for (int n = 0; n < 4; n++) {
    const int col = n0 + wc * 64 + n * 16 + l15;
    const float bv = bias[col];
#pragma unroll
    for (int m = 0; m < 4; m++) {
      const int row0 = m0 + wr * 64 + m * 16 + lg * 4;
#pragma unroll
      for (int r = 0; r < 4; r++) {
        float v = acc[m][n][r] + bv;
        Y[(size_t)(row0 + r) * 1024 + col] = v > 0.f ? v : 0.f;
      }
    }
  }
}

// ------ key padding mask as bitmask: bit(row%32) of word[row/32] ----------
__global__ __launch_bounds__(256) void key_mask_kernel(const short* Kb_,
                                                       unsigned* __restrict__ kbits) {
  __shared__ unsigned bits[4];
  const bf16* Kb = (const bf16*)Kb_;
  const int wid = threadIdx.x >> 6, lane = threadIdx.x & 63;
  const int row0 = blockIdx.x * 32 + wid * 8;
  unsigned mybits = 0;
#pragma unroll
  for (int i = 0; i < 8; i++) {
    const bf16x8* p = (const bf16x8*)(Kb + (size_t)(row0 + i) * 1024);
    bf16x8 v0 = p[lane];
    bf16x8 v1 = p[64 + lane];
    float s = 0.f;
#pragma unroll
    for (int jj = 0; jj < 8; jj++) s += (float)v0[jj] + (float)v1[jj];
    for (int m = 32; m; m >>= 1) s += __shfl_xor(s, m);
    if (s != 0.f) mybits |= 1u << (wid * 8 + i);
  }
  if (lane == 0) bits[wid] = mybits;
  __syncthreads();
  if (threadIdx.x == 0) kbits[blockIdx.x] = bits[0] | bits[1] | bits[2] | bits[3];
}

// ---------------- causal flash attention, v7 -------------------------------
// 2048 blocks x 64 threads (ONE wave): no barriers at all. QROWS=32 (2 m-
// frags), KVBLK=32. LDS 18KB -> 8 blocks/CU, all 2048 resident.
// Counted-vmcnt dbuf pipeline: stage tile t+1, s_waitcnt vmcnt(8), compute t.
// Softmax denominator accumulated by MFMA with an all-ones B operand (L
// rescales with O automatically). Deferred-max gate: ONE dpp chain per iter;
// full per-row max recompute only when a rescale triggers.
// Tile map t(j): even/odd complement folded over bit5 -> any contiguous-8 or
// stride-32 CU assignment gets a near-equal iteration sum.
__device__ __forceinline__ bf16x8 ldsK(const bf16* base, int row, int cb) {
  return *(const bf16x8*)((const char*)base + row * 128 + (cb ^ ((row & 7) << 4)));
}
__device__ __forceinline__ bf16x8 lds64(const bf16* base, int row, int cb) {
  return *(const bf16x8*)((const char*)base + row * 64 + (cb ^ (((row >> 1) & 3) << 4)));
}

__global__ __launch_bounds__(64) void attn_kernel(
    const short* Q_, const short* K_, const short* Vt_,
    const unsigned* __restrict__ kbits, short* O_) {
  __shared__ bf16 Klds[2][32][64];   // [key][d], 128B rows, swz (row&7)<<4
  __shared__ bf16 Vlds[2][64][32];   // [d][tok], 64B rows, swz ((row>>1)&3)<<4
  __shared__ bf16 Plds[32][32];      // [q][key], 64B rows, swz ((row>>1)&3)<<4
  const bf16* Q = (const bf16*)Q_;
  const bf16* K = (const bf16*)K_;
  const bf16* Vt = (const bf16*)Vt_;
  bf16* O = (bf16*)O_;

  const int f = blockIdx.x;
  const int xcd = f & 7, idx = f >> 3;
  const int hbp = idx >> 6, j = idx & 63;
  const int jj = j & 31;
  const int tb = (jj & 1) ? 63 - jj : jj;       // evens for j<32
  const int t = (j & 32) ? 63 - tb : tb;         // odds for j>=32
  const int hb = xcd + 8 * hbp;
  const int h = hb & 15, b = hb >> 4;
  const int q0 = t * 32, nkt = t + 1;

  const int lane = threadIdx.x;
  const int l15 = lane & 15, lg = lane >> 4;
  const f32x4 vzero = {0.f, 0.f, 0.f, 0.f};

  // staging lane geometry (pre-swizzled global source columns)
  const int ksrow = lane >> 3;                               // 0..7
  const int kcb = ((lane & 7) * 16) ^ (ksrow << 4);
  const int vsrow = lane >> 2;                               // 0..15
  const int vcb = ((lane & 3) * 16) ^ (((vsrow >> 1) & 3) << 4);

  // Q fragments (pre-scaled by SCL2 in qkv_gemm)
  bf16x8 qf[2][2];
#pragma unroll
  for (int m = 0; m < 2; m++) {
    const bf16* qp = Q + ((size_t)b * 2048 + q0 + m * 16 + l15) * 1024 + h * 64;
#pragma unroll
    for (int ks = 0; ks < 2; ks++) qf[m][ks] = *(const bf16x8*)(qp + ks * 32 + lg * 8);
  }

  // all-ones bf16 B-fragment for the L (row-sum) MFMA
  bf16x8 vones;
#pragma unroll
  for (int i = 0; i < 8; i++) vones[i] = (bf16)1.0f;

  float Mrow[2][4];
  f32x4 oacc[2][4], oaccL[2];
#pragma unroll
  for (int m = 0; m < 2; m++) {
#pragma unroll
    for (int r = 0; r < 4; r++) Mrow[m][r] = -INFINITY;
#pragma unroll
    for (int nd = 0; nd < 4; nd++) oacc[m][nd] = vzero;
    oaccL[m] = vzero;
  }
  float Mmin = -INFINITY;

  auto STAGE = [&](int buf, int kt) {
#pragma unroll
    for (int c = 0; c < 4; c++) {
      const char* gk = (const char*)(K + ((size_t)b * 2048 + kt * 32 + c * 8 + ksrow) * 1024 + h * 64) + kcb;
      async_cp16(gk, &Klds[buf][c * 8][0]);
    }
#pragma unroll
    for (int c = 0; c < 4; c++) {
      const char* gv = (const char*)(Vt + ((size_t)b * 1024 + h * 64 + c * 16 + vsrow) * 2048 + kt * 32) + vcb;
      async_cp16(gv, &Vlds[buf][c * 16][0]);
    }
  };

  STAGE(0, 0);
  int cur = 0;
  for (int kt = 0; kt < nkt; ++kt) {
    if (kt + 1 < nkt) {
      STAGE(cur ^ 1, kt + 1);
      asm volatile("s_waitcnt vmcnt(8)" ::: "memory");
    } else {
      asm volatile("s_waitcnt vmcnt(0)" ::: "memory");
    }
    __builtin_amdgcn_sched_barrier(0);

    // ---- S = Q K^T ----
    f32x4 sacc[2][2];
#pragma unroll
    for (int m = 0; m < 2; m++)
#pragma unroll
      for (int n = 0; n < 2; n++) sacc[m][n] = vzero;
#pragma unroll
    for (int ks = 0; ks < 2; ks++) {
      bf16x8 kf0 = ldsK(&Klds[cur][0][0], l15, ks * 64 + lg * 16);
      bf16x8 kf1 = ldsK(&Klds[cur][0][0], 16 + l15, ks * 64 + lg * 16);
      __builtin_amdgcn_s_setprio(1);
#pragma unroll
      for (int m = 0; m < 2; m++) {
        sacc[m][0] = __builtin_amdgcn_mfma_f32_16x16x32_bf16(qf[m][ks], kf0, sacc[m][0], 0, 0, 0);
        sacc[m][1] = __builtin_amdgcn_mfma_f32_16x16x32_bf16(qf[m][ks], kf1, sacc[m][1], 0, 0, 0);
      }
      __builtin_amdgcn_s_setprio(0);
    }

    // ---- key-padding bitmask (+ causal on last tile) ----
    const unsigned wb = kbits[(b << 6) + kt];
#pragma unroll
    for (int n = 0; n < 2; n++) {
      const bool on = (wb >> (n * 16 + l15)) & 1;
      if (!on) {
#pragma unroll
        for (int m = 0; m < 2; m++)
#pragma unroll
          for (int r = 0; r < 4; r++) sacc[m][n][r] = NEGV;
      }
    }
    if (kt == nkt - 1) {
#pragma unroll
      for (int m = 0; m < 2; m++)
#pragma unroll
        for (int n = 0; n < 2; n++) {
          const int c16 = n * 16 + l15;
#pragma unroll
          for (int r = 0; r < 4; r++)
            if (c16 > m * 16 + lg * 4 + r) sacc[m][n][r] = NEGV;
        }
    }

    // ---- deferred-max gate (one dpp chain) ----
    {
      float lm = sacc[0][0][0];
#pragma unroll
      for (int m = 0; m < 2; m++)
#pragma unroll
        for (int n = 0; n < 2; n++)
#pragma unroll
          for (int r = 0; r < 4; r++) lm = fmaxf(lm, sacc[m][n][r]);
      const float gmax = dpp_max16(lm);
      if (!__all(gmax <= Mmin + 8.f)) {
        // rescale path: per-row max + rescale of O and L
#pragma unroll
        for (int m = 0; m < 2; m++)
#pragma unroll
          for (int r = 0; r < 4; r++) {
            float tm = fmaxf(sacc[m][0][r], sacc[m][1][r]);
            tm = dpp_max16(tm);
            const float Mn = fmaxf(Mrow[m][r], tm);
            const float sc = exp2f(Mrow[m][r] - Mn);
            Mrow[m][r] = Mn;
#pragma unroll
            for (int nd = 0; nd < 4; nd++) oacc[m][nd][r] *= sc;
            oaccL[m][r] *= sc;
          }
        float mm = Mrow[0][0];
#pragma unroll
        for (int m = 0; m < 2; m++)
#pragma unroll
          for (int r = 0; r < 4; r++) mm = fminf(mm, Mrow[m][r]);
        Mmin = mm;
      }
    }

    // ---- P = exp2(S - M) -> LDS ----
#pragma unroll
    for (int m = 0; m < 2; m++)
#pragma unroll
      for (int n = 0; n < 2; n++)
#pragma unroll
        for (int r = 0; r < 4; r++) {
          const float p = exp2f(sacc[m][n][r] - Mrow[m][r]);
          const int prow = m * 16 + lg * 4 + r;
          *(bf16*)((char*)&Plds[0][0] + prow * 64 +
                   (((n * 16 + l15) * 2) ^ (((prow >> 1) & 3) << 4))) = (bf16)p;
        }

    // ---- O += P V ; L += P * 1 ----
    {
      bf16x8 pf0 = lds64(&Plds[0][0], l15, lg * 16);
      bf16x8 pf1 = lds64(&Plds[0][0], 16 + l15, lg * 16);
      bf16x8 vf[4];
#pragma unroll
      for (int nd = 0; nd < 4; nd++)
        vf[nd] = lds64(&Vlds[cur][0][0], nd * 16 + l15, lg * 16);
      __builtin_amdgcn_s_setprio(1);
#pragma unroll
      for (int nd = 0; nd < 4; nd++) {
        oacc[0][nd] = __builtin_amdgcn_mfma_f32_16x16x32_bf16(pf0, vf[nd], oacc[0][nd], 0, 0, 0);
        oacc[1][nd] = __builtin_amdgcn_mfma_f32_16x16x32_bf16(pf1, vf[nd], oacc[1][nd], 0, 0, 0);
      }
      oaccL[0] = __builtin_amdgcn_mfma_f32_16x16x32_bf16(pf0, vones, oaccL[0], 0, 0, 0);
      oaccL[1] = __builtin_amdgcn_mfma_f32_16x16x32_bf16(pf1, vones, oaccL[1], 0, 0, 0);
      __builtin_amdgcn_s_setprio(0);
    }

    cur ^= 1;
  }

  // ---- epilogue: O /= L ----
#pragma unroll
  for (int m = 0; m < 2; m++) {
    float inv[4];
#pragma unroll
    for (int r = 0; r < 4; r++) inv[r] = 1.0f / oaccL[m][r];
#pragma unroll
    for (int nd = 0; nd < 4; nd++) {
      const int col = h * 64 + nd * 16 + l15;
#pragma unroll
      for (int r = 0; r < 4; r++) {
        const float v = oacc[m][nd][r] * inv[r];
        O[((size_t)b * 2048 + q0 + m * 16 + lg * 4 + r) * 1024 + col] = (bf16)v;
      }
    }
  }
}

// ---------------- residual + LayerNorm (unbiased std, eps on std) ---------
__global__ __launch_bounds__(256) void ln_kernel(const float* __restrict__ qin,
                                                 const float* __restrict__ proj,
                                                 float* __restrict__ out) {
  __shared__ float sbuf[4];
  const int row = blockIdx.x, tid = threadIdx.x;
  const size_t base = (size_t)row * 1024 + tid * 4;
  const float4 a = *(const float4*)(qin + base);
  const float4 p = *(const float4*)(proj + base);
  const float x0 = a.x + p.x, x1 = a.y + p.y, x2 = a.z + p.z, x3 = a.w + p.w;
  float s = x0 + x1 + x2 + x3;
  for (int m = 32; m; m >>= 1) s += __shfl_xor(s, m);
  if ((tid & 63) == 0) sbuf[tid >> 6] = s;
  __syncthreads();
  s = sbuf[0] + sbuf[1] + sbuf[2] + sbuf[3];
  const float mean = s * (1.f / 1024.f);
  const float d0 = x0 - mean, d1 = x1 - mean, d2 = x2 - mean, d3 = x3 - mean;
  float ss = d0 * d0 + d1 * d1 + d2 * d2 + d3 * d3;
  __syncthreads();
  for (int m = 32; m; m >>= 1) ss += __shfl_xor(ss, m);
  if ((tid & 63) == 0) sbuf[tid >> 6] = ss;
  __syncthreads();
  ss = sbuf[0] + sbuf[1] + sbuf[2] + sbuf[3];
  const float inv = 1.f / (sqrtf(ss * (1.f / 1023.f)) + 1e-8f);
  float4 o;
  o.x = d0 * inv; o.y = d1 * inv; o.z = d2 * inv; o.w = d3 * inv;
  *(float4*)(out + base) = o;
}

// ---------------- host orchestration --------------------------------------
extern "C" void kernel_launch(void* const* d_in, const int* in_sizes, int n_in,
                              void* d_out, int out_size, void* d_ws, size_t ws_size,
                              hipStream_t stream) {
  (void)in_sizes; (void)n_in; (void)out_size; (void)ws_size;
  const float* queries = (const float*)d_in[0];
  const float* keys    = (const float*)d_in[1];
  const float* values  = (const float*)d_in[2];
  const float* Wq = (const float*)d_in[3];  const float* bq = (const float*)d_in[4];
  const float* Wk = (const float*)d_in[5];  const float* bk = (const float*)d_in[6];
  const float* Wv = (const float*)d_in[7];  const float* bv = (const float*)d_in[8];
  const float* Wo = (const float*)d_in[9];  const float* bo = (const float*)d_in[10];
  float* out = (float*)d_out;

  char* w = (char*)d_ws;
  const size_t SZ_X = (size_t)4096 * 1024 * 2;   // 8 MB (bf16 [4096,1024])
  const size_t SZ_W = (size_t)1024 * 1024 * 2;   // 2 MB
  short* Xq  = (short*)w; w += SZ_X;
  short* Xk  = (short*)w; w += SZ_X;
  short* Xv  = (short*)w; w += SZ_X;
  short* Wtq = (short*)w; w += SZ_W;
  short* Wtk = (short*)w; w += SZ_W;
  short* Wtv = (short*)w; w += SZ_W;
  short* Wto = (short*)w; w += SZ_W;
  short* Qb  = (short*)w; w += SZ_X;
  short* Kb  = (short*)w; w += SZ_X;
  short* Vtb = (short*)w; w += SZ_X;
  short* Ab  = (short*)w; w += SZ_X;
  unsigned* kbits = (unsigned*)w; w += 4096;
  float* proj = (float*)w; w += (size_t)4096 * 1024 * 4;

  cvt3_kernel<<<12288, 256, 0, stream>>>(queries, keys, values, Xq, Xk, Xv);
  wt_kernel<<<dim3(16, 16, 4), 256, 0, stream>>>(Wq, Wk, Wv, Wo, Wtq, Wtk, Wtv, Wto);
  qkv_gemm<<<dim3(8, 32, 3), 256, 0, stream>>>(Xq, Xk, Xv, Wtq, Wtk, Wtv,
                                               bq, bk, bv, Qb, Kb, Vtb);
  key_mask_kernel<<<128, 256, 0, stream>>>(Kb, kbits);
  attn_kernel<<<2048, 64, 0, stream>>>(Qb, Kb, Vtb, kbits, Ab);
  out_gemm<<<dim3(8, 32), 256, 0, stream>>>(Ab, Wto, bo, proj);
  ln_kernel<<<4096, 256, 0, stream>>>(queries, proj, out);
}

// Round 10
// 158.495 us; speedup vs baseline: 1.1468x; 1.1468x over previous
//
#include <hip/hip_runtime.h>
#include <math.h>

typedef __bf16 bf16;
typedef __attribute__((ext_vector_type(8))) __bf16 bf16x8;
typedef __attribute__((ext_vector_type(4))) __bf16 bf16x4;
typedef __attribute__((ext_vector_type(4))) float f32x4;

typedef __attribute__((address_space(1))) unsigned int glb_u32;
typedef __attribute__((address_space(3))) unsigned int lds_u32;

#define NEGV (-4294967295.0f)
#define SCL2 0.18033688011112042f  /* 0.125 * log2(e), folded into Q */

__device__ __forceinline__ void async_cp16(const void* g, void* l) {
  __builtin_amdgcn_global_load_lds((glb_u32*)g, (lds_u32*)l, 16, 0, 0);
}

// ---- DPP 16-lane butterfly reduce (VALU pipe, not LDS) --------------------
template <int CTRL>
__device__ __forceinline__ float dppf(float x) {
  return __builtin_bit_cast(float,
      __builtin_amdgcn_mov_dpp(__builtin_bit_cast(int, x), CTRL, 0xF, 0xF, true));
}
__device__ __forceinline__ float dpp_max16(float x) {
  x = fmaxf(x, dppf<0xB1>(x));   // quad_perm xor1
  x = fmaxf(x, dppf<0x4E>(x));   // quad_perm xor2
  x = fmaxf(x, dppf<0x141>(x));  // row_half_mirror
  x = fmaxf(x, dppf<0x140>(x));  // row_mirror
  return x;
}

// ---------------- fp32 -> bf16 convert, all three inputs in one launch ----
__global__ __launch_bounds__(256) void cvt3_kernel(
    const float* __restrict__ q, const float* __restrict__ k,
    const float* __restrict__ v, short* xq, short* xk, short* xv) {
  const int bid = blockIdx.x;
  const int which = bid >> 12;           // 0..2
  const int i = (bid & 4095) * 256 + threadIdx.x;
  const float* src = which == 0 ? q : (which == 1 ? k : v);
  short* dst = which == 0 ? xq : (which == 1 ? xk : xv);
  float4 vv = ((const float4*)src)[i];
  bf16x4 o;
  o[0] = (bf16)vv.x; o[1] = (bf16)vv.y; o[2] = (bf16)vv.z; o[3] = (bf16)vv.w;
  ((bf16x4*)dst)[i] = o;
}

// ---------------- weight transpose + convert: T[n][k] = W[k][n] -----------
__global__ __launch_bounds__(256) void wt_kernel(
    const float* __restrict__ W0, const float* __restrict__ W1,
    const float* __restrict__ W2, const float* __restrict__ W3,
    short* T0, short* T1, short* T2, short* T3) {
  __shared__ float tile[64][65];
  const float* W = blockIdx.z == 0 ? W0 : (blockIdx.z == 1 ? W1 : (blockIdx.z == 2 ? W2 : W3));
  bf16* T = (bf16*)(blockIdx.z == 0 ? T0 : (blockIdx.z == 1 ? T1 : (blockIdx.z == 2 ? T2 : T3)));
  const int k0 = blockIdx.y * 64, n0 = blockIdx.x * 64;
  const int tid = threadIdx.x;
  const int c = tid & 63, rr = tid >> 6;
#pragma unroll
  for (int i = 0; i < 16; i++) {
    int r = i * 4 + rr;
    tile[r][c] = W[(size_t)(k0 + r) * 1024 + n0 + c];
  }
  __syncthreads();
#pragma unroll
  for (int i = 0; i < 16; i++) {
    int r = i * 4 + rr;
    T[(size_t)(n0 + r) * 1024 + k0 + c] = (bf16)tile[c][r];
  }
}

// ---------------- QKV projection GEMM: Y = relu(X @ W + b) ----------------
__global__ __launch_bounds__(256) void qkv_gemm(
    const short* Xq_, const short* Xk_, const short* Xv_,
    const short* Wtq_, const short* Wtk_, const short* Wtv_,
    const float* __restrict__ bq_, const float* __restrict__ bk_, const float* __restrict__ bv_,
    short* Qo_, short* Ko_, short* Vto_) {
  __shared__ bf16 Alds[128][32];
  __shared__ bf16 Blds[128][32];
  const int which = blockIdx.z;
  const bf16* X  = (const bf16*)(which == 0 ? Xq_  : (which == 1 ? Xk_  : Xv_));
  const bf16* Wt = (const bf16*)(which == 0 ? Wtq_ : (which == 1 ? Wtk_ : Wtv_));
  const float* bias = which == 0 ? bq_ : (which == 1 ? bk_ : bv_);
  const int m0 = blockIdx.y * 128, n0 = blockIdx.x * 128;
  const int tid = threadIdx.x, wid = tid >> 6, lane = tid & 63;
  const int wr = wid >> 1, wc = wid & 1;
  const int l15 = lane & 15, lg = lane >> 4;
  const f32x4 vzero = {0.f, 0.f, 0.f, 0.f};
  f32x4 acc[4][4];
#pragma unroll
  for (int m = 0; m < 4; m++)
#pragma unroll
    for (int n = 0; n < 4; n++) acc[m][n] = vzero;

  const int sr = wid * 32 + (lane >> 2);
  const int scb = (lane & 3) * 16;

  for (int kt = 0; kt < 32; ++kt) {
    const char* ga = (const char*)(X + (size_t)(m0 + sr) * 1024 + kt * 32) + scb;
    async_cp16(ga, &Alds[wid * 32][0]);
    async_cp16(ga + 16 * 2048, &Alds[wid * 32 + 16][0]);
    const char* gb = (const char*)(Wt + (size_t)(n0 + sr) * 1024 + kt * 32) + scb;
    async_cp16(gb, &Blds[wid * 32][0]);
    async_cp16(gb + 16 * 2048, &Blds[wid * 32 + 16][0]);
    __syncthreads();
    bf16x8 a[4], bb[4];
#pragma unroll
    for (int m = 0; m < 4; m++) a[m] = *(const bf16x8*)&Alds[wr * 64 + m * 16 + l15][lg * 8];
#pragma unroll
    for (int n = 0; n < 4; n++) bb[n] = *(const bf16x8*)&Blds[wc * 64 + n * 16 + l15][lg * 8];
#pragma unroll
    for (int m = 0; m < 4; m++)
#pragma unroll
      for (int n = 0; n < 4; n++)
        acc[m][n] = __builtin_amdgcn_mfma_f32_16x16x32_bf16(a[m], bb[n], acc[m][n], 0, 0, 0);
    __syncthreads();
  }

  if (which != 2) {
    bf16* Y = (bf16*)(which == 0 ? Qo_ : Ko_);
    const float osc = (which == 0) ? SCL2 : 1.0f;
#pragma unroll
    for (int n = 0; n < 4; n++) {
      const int col = n0 + wc * 64 + n * 16 + l15;
      const float bv = bias[col];
#pragma unroll
      for (int m = 0; m < 4; m++) {
        const int row0 = m0 + wr * 64 + m * 16 + lg * 4;
#pragma unroll
        for (int r = 0; r < 4; r++) {
          float v = acc[m][n][r] + bv;
          v = v > 0.f ? v : 0.f;
          Y[(size_t)(row0 + r) * 1024 + col] = (bf16)(v * osc);
        }
      }
    }
  } else {
    bf16* Vt = (bf16*)Vto_;
#pragma unroll
    for (int n = 0; n < 4; n++) {
      const int col = n0 + wc * 64 + n * 16 + l15;
      const float bv = bias[col];
#pragma unroll
      for (int m = 0; m < 4; m++) {
        const int row0 = m0 + wr * 64 + m * 16 + lg * 4;
        const int bb2 = row0 >> 11;
        const int s = row0 & 2047;
        bf16x4 pk;
#pragma unroll
        for (int r = 0; r < 4; r++) {
          float v = acc[m][n][r] + bv;
          v = v > 0.f ? v : 0.f;
          pk[r] = (bf16)v;
        }
        *(bf16x4*)(Vt + ((size_t)bb2 * 1024 + col) * 2048 + s) = pk;
      }
    }
  }
}

// ---------------- output projection GEMM (fp32 out, no transpose) ---------
__global__ __launch_bounds__(256) void out_gemm(
    const short* A_, const short* Wt_, const float* __restrict__ bias,
    float* __restrict__ Y) {
  __shared__ bf16 Alds[128][32];
  __shared__ bf16 Blds[128][32];
  const bf16* X = (const bf16*)A_;
  const bf16* Wt = (const bf16*)Wt_;
  const int m0 = blockIdx.y * 128, n0 = blockIdx.x * 128;
  const int tid = threadIdx.x, wid = tid >> 6, lane = tid & 63;
  const int wr = wid >> 1, wc = wid & 1;
  const int l15 = lane & 15, lg = lane >> 4;
  const f32x4 vzero = {0.f, 0.f, 0.f, 0.f};
  f32x4 acc[4][4];
#pragma unroll
  for (int m = 0; m < 4; m++)
#pragma unroll
    for (int n = 0; n < 4; n++) acc[m][n] = vzero;

  const int sr = wid * 32 + (lane >> 2);
  const int scb = (lane & 3) * 16;

  for (int kt = 0; kt < 32; ++kt) {
    const char* ga = (const char*)(X + (size_t)(m0 + sr) * 1024 + kt * 32) + scb;
    async_cp16(ga, &Alds[wid * 32][0]);
    async_cp16(ga + 16 * 2048, &Alds[wid * 32 + 16][0]);
    const char* gb = (const char*)(Wt + (size_t)(n0 + sr) * 1024 + kt * 32) + scb;
    async_cp16(gb, &Blds[wid * 32][0]);
    async_cp16(gb + 16 * 2048, &Blds[wid * 32 + 16][0]);
    __syncthreads();
    bf16x8 a[4], bb[4];
#pragma unroll
    for (int m = 0; m < 4; m++) a[m] = *(const bf16x8*)&Alds[wr * 64 + m * 16 + l15][lg * 8];
#pragma unroll
    for (int n = 0; n < 4; n++) bb[n] = *(const bf16x8*)&Blds[wc * 64 + n * 16 + l15][lg * 8];
#pragma unroll
    for (int m = 0; m < 4; m++)
#pragma unroll
      for (int n = 0; n < 4; n++)
        acc[m][n] = __builtin_amdgcn_mfma_f32_16x16x32_bf16(a[m], bb[n], acc[m][n], 0, 0, 0);
    __syncthreads();
  }
#pragma unroll
  for (int n = 0; n < 4; n++) {
    const int col = n0 + wc * 64 + n * 16 + l15;
    const float bv = bias[col];
#pragma unroll
    for (int m = 0; m < 4; m++) {
      const int row0 = m0 + wr * 64 + m * 16 + lg * 4;
#pragma unroll
      for (int r = 0; r < 4; r++) {
        float v = acc[m][n][r] + bv;
        Y[(size_t)(row0 + r) * 1024 + col] = v > 0.f ? v : 0.f;
      }
    }
  }
}

// ------ key padding mask as bitmask: bit(row%32) of word[row/32] ----------
__global__ __launch_bounds__(256) void key_mask_kernel(const short* Kb_,
                                                       unsigned* __restrict__ kbits) {
  __shared__ unsigned bits[4];
  const bf16* Kb = (const bf16*)Kb_;
  const int wid = threadIdx.x >> 6, lane = threadIdx.x & 63;
  const int row0 = blockIdx.x * 32 + wid * 8;
  unsigned mybits = 0;
#pragma unroll
  for (int i = 0; i < 8; i++) {
    const bf16x8* p = (const bf16x8*)(Kb + (size_t)(row0 + i) * 1024);
    bf16x8 v0 = p[lane];
    bf16x8 v1 = p[64 + lane];
    float s = 0.f;
#pragma unroll
    for (int jj = 0; jj < 8; jj++) s += (float)v0[jj] + (float)v1[jj];
    for (int m = 32; m; m >>= 1) s += __shfl_xor(s, m);
    if (s != 0.f) mybits |= 1u << (wid * 8 + i);
  }
  if (lane == 0) bits[wid] = mybits;
  __syncthreads();
  if (threadIdx.x == 0) kbits[blockIdx.x] = bits[0] | bits[1] | bits[2] | bits[3];
}

// ---------------- causal flash attention, v8 -------------------------------
// R7 geometry (proven 81us): 1024 blocks x 128 thr (2 waves), qt<->63-qt
// pairing = exactly 33 KVBLK=64 iters/block, XCD remap, dbuf K/V LDS.
// v7 ports: MFMA-ones L row-sum (no dpp_sum chains; L auto-rescales with O),
// single-dpp-chain deferred-max gate, kbits bitmask for key padding.
__device__ __forceinline__ bf16x8 lds_read_swz(const bf16* base, int row, int cbyte) {
  return *(const bf16x8*)((const char*)base + row * 128 + (cbyte ^ ((row & 7) << 4)));
}

__global__ __launch_bounds__(128) void attn_kernel(
    const short* Q_, const short* K_, const short* Vt_,
    const unsigned* __restrict__ kbits, short* O_) {
  __shared__ bf16 Klds[2][64][64];
  __shared__ bf16 Vlds[2][64][64];
  __shared__ bf16 Plds[2][16][64];
  const bf16* Q = (const bf16*)Q_;
  const bf16* K = (const bf16*)K_;
  const bf16* Vt = (const bf16*)Vt_;
  bf16* O = (bf16*)O_;

  // bijective XCD-grouping decode: all blocks of one (h,b) on one XCD
  const int f = blockIdx.x;
  const int xcd = f & 7, idx = f >> 3;
  const int qtb = idx & 31;
  const int hb = xcd + 8 * (idx >> 5);   // 0..31
  const int h = hb & 15, b = hb >> 4;

  const int tid = threadIdx.x, wid = tid >> 6, lane = tid & 63;
  const int l15 = lane & 15, lg = lane >> 4;
  const f32x4 vzero = {0.f, 0.f, 0.f, 0.f};
  bf16* const pbase = &Plds[wid][0][0];

  // staging geometry: 8 lanes per 128B row; one call = 8 rows; 4 calls/wave
  const int srow = lane >> 3;        // 0..7
  const int cb = (lane & 7) * 16;    // byte col in 128B row
  const int cbs = cb ^ ((srow & 7) << 4);  // pre-swizzled source col

  // all-ones bf16 B-fragment for the L (row-sum) MFMA
  bf16x8 vones;
#pragma unroll
  for (int i = 0; i < 8; i++) vones[i] = (bf16)1.0f;

  for (int seg = 0; seg < 2; ++seg) {
    const int qt = (seg == 0) ? qtb : 63 - qtb;
    const int q0 = qt * 32;
    const int nkt = (32 * qt + 95) >> 6;

    // Q fragments (pre-scaled by SCL2 in qkv_gemm)
    const int qrow = q0 + wid * 16 + l15;
    const bf16* qp = Q + ((size_t)b * 2048 + qrow) * 1024 + h * 64;
    const bf16x8 qf0 = *(const bf16x8*)(qp + lg * 8);
    const bf16x8 qf1 = *(const bf16x8*)(qp + 32 + lg * 8);

    float Mrow[4];
    f32x4 oacc[4], oaccL;
#pragma unroll
    for (int r = 0; r < 4; r++) Mrow[r] = -INFINITY;
#pragma unroll
    for (int n = 0; n < 4; n++) oacc[n] = vzero;
    oaccL = vzero;
    float Mmin = -INFINITY;

    // ---- stage K+V tile kt into buffer buf ----
    auto STAGE = [&](int buf, int kt) {
#pragma unroll
      for (int c = 0; c < 4; c++) {
        const int r = wid * 32 + c * 8 + srow;
        const char* gk = (const char*)(K + ((size_t)b * 2048 + kt * 64 + r) * 1024 + h * 64);
        async_cp16(gk + cbs, &Klds[buf][wid * 32 + c * 8][0]);
        const char* gv = (const char*)(Vt + ((size_t)b * 1024 + h * 64 + r) * 2048 + kt * 64);
        async_cp16(gv + cbs, &Vlds[buf][wid * 32 + c * 8][0]);
      }
    };

    STAGE(0, 0);
    __syncthreads();
    int cur = 0;
    for (int kt = 0; kt < nkt; ++kt) {
      if (kt + 1 < nkt) STAGE(cur ^ 1, kt + 1);

      // ---- S = Q K^T (scale already folded into Q) ----
      f32x4 sacc[4];
#pragma unroll
      for (int n = 0; n < 4; n++) sacc[n] = vzero;
      {
        bf16x8 kf[4];
#pragma unroll
        for (int n = 0; n < 4; n++)
          kf[n] = lds_read_swz(&Klds[cur][0][0], n * 16 + l15, lg * 16);
        __builtin_amdgcn_s_setprio(1);
#pragma unroll
        for (int n = 0; n < 4; n++)
          sacc[n] = __builtin_amdgcn_mfma_f32_16x16x32_bf16(qf0, kf[n], sacc[n], 0, 0, 0);
        __builtin_amdgcn_s_setprio(0);
#pragma unroll
        for (int n = 0; n < 4; n++)
          kf[n] = lds_read_swz(&Klds[cur][0][0], n * 16 + l15, 64 + lg * 16);
        __builtin_amdgcn_s_setprio(1);
#pragma unroll
        for (int n = 0; n < 4; n++)
          sacc[n] = __builtin_amdgcn_mfma_f32_16x16x32_bf16(qf1, kf[n], sacc[n], 0, 0, 0);
        __builtin_amdgcn_s_setprio(0);
      }

      // ---- key-padding bitmask (+ causal on last tile only) ----
      const unsigned w0 = kbits[b * 64 + kt * 2];
      const unsigned w1 = kbits[b * 64 + kt * 2 + 1];
      const int qrow0 = q0 + wid * 16 + lg * 4;
      const bool last = (kt == nkt - 1);
#pragma unroll
      for (int n = 0; n < 4; n++) {
        const unsigned wsel = (n < 2) ? w0 : w1;
        const bool on = (wsel >> ((n & 1) * 16 + l15)) & 1;
        const int kcol = kt * 64 + n * 16 + l15;
#pragma unroll
        for (int r = 0; r < 4; r++) {
          float sc = sacc[n][r];
          if (!on) sc = NEGV;
          if (last && kcol > qrow0 + r) sc = NEGV;
          sacc[n][r] = sc;
        }
      }

      // ---- deferred-max gate: ONE dpp chain on the common path ----
      {
        float lm = sacc[0][0];
#pragma unroll
        for (int n = 0; n < 4; n++)
#pragma unroll
          for (int r = 0; r < 4; r++) lm = fmaxf(lm, sacc[n][r]);
        const float gmax = dpp_max16(lm);
        if (!__all(gmax <= Mmin + 8.f)) {
          // rescale path (rare): per-row max + rescale O and L
#pragma unroll
          for (int r = 0; r < 4; r++) {
            float tm = fmaxf(fmaxf(sacc[0][r], sacc[1][r]), fmaxf(sacc[2][r], sacc[3][r]));
            tm = dpp_max16(tm);
            const float Mn = fmaxf(Mrow[r], tm);
            const float sc = exp2f(Mrow[r] - Mn);
            Mrow[r] = Mn;
#pragma unroll
            for (int n = 0; n < 4; n++) oacc[n][r] *= sc;
            oaccL[r] *= sc;
          }
          Mmin = fminf(fminf(Mrow[0], Mrow[1]), fminf(Mrow[2], Mrow[3]));
        }
      }

      // ---- P = exp2(S - M) -> per-wave LDS ----
#pragma unroll
      for (int n = 0; n < 4; n++)
#pragma unroll
        for (int r = 0; r < 4; r++) {
          const float p = exp2f(sacc[n][r] - Mrow[r]);
          const int prow = lg * 4 + r;
          *(bf16*)((char*)pbase + prow * 128 +
                   (((n * 16 + l15) * 2) ^ ((prow & 7) << 4))) = (bf16)p;
        }

      // ---- O += P V ; L += P * 1 ----
#pragma unroll
      for (int ks = 0; ks < 2; ks++) {
        bf16x8 vf[4];
#pragma unroll
        for (int nd = 0; nd < 4; nd++)
          vf[nd] = lds_read_swz(&Vlds[cur][0][0], nd * 16 + l15, ks * 64 + lg * 16);
        const bf16x8 pf = lds_read_swz(pbase, l15, ks * 64 + lg * 16);
        __builtin_amdgcn_s_setprio(1);
#pragma unroll
        for (int nd = 0; nd < 4; nd++)
          oacc[nd] = __builtin_amdgcn_mfma_f32_16x16x32_bf16(pf, vf[nd], oacc[nd], 0, 0, 0);
        oaccL = __builtin_amdgcn_mfma_f32_16x16x32_bf16(pf, vones, oaccL, 0, 0, 0);
        __builtin_amdgcn_s_setprio(0);
      }

      __syncthreads();
      cur ^= 1;
    }

    // ---- epilogue: O /= L ----
    float inv[4];
#pragma unroll
    for (int r = 0; r < 4; r++) inv[r] = 1.0f / oaccL[r];
#pragma unroll
    for (int nd = 0; nd < 4; nd++) {
      const int col = h * 64 + nd * 16 + l15;
#pragma unroll
      for (int r = 0; r < 4; r++) {
        const float v = oacc[nd][r] * inv[r];
        O[((size_t)b * 2048 + q0 + wid * 16 + lg * 4 + r) * 1024 + col] = (bf16)v;
      }
    }
  }
}

// ---------------- residual + LayerNorm (unbiased std, eps on std) ---------
__global__ __launch_bounds__(256) void ln_kernel(const float* __restrict__ qin,
                                                 const float* __restrict__ proj,
                                                 float* __restrict__ out) {
  __shared__ float sbuf[4];
  const int row = blockIdx.x, tid = threadIdx.x;
  const size_t base = (size_t)row * 1024 + tid * 4;
  const float4 a = *(const float4*)(qin + base);
  const float4 p = *(const float4*)(proj + base);
  const float x0 = a.x + p.x, x1 = a.y + p.y, x2 = a.z + p.z, x3 = a.w + p.w;
  float s = x0 + x1 + x2 + x3;
  for (int m = 32; m; m >>= 1) s += __shfl_xor(s, m);
  if ((tid & 63) == 0) sbuf[tid >> 6] = s;
  __syncthreads();
  s = sbuf[0] + sbuf[1] + sbuf[2] + sbuf[3];
  const float mean = s * (1.f / 1024.f);
  const float d0 = x0 - mean, d1 = x1 - mean, d2 = x2 - mean, d3 = x3 - mean;
  float ss = d0 * d0 + d1 * d1 + d2 * d2 + d3 * d3;
  __syncthreads();
  for (int m = 32; m; m >>= 1) ss += __shfl_xor(ss, m);
  if ((tid & 63) == 0) sbuf[tid >> 6] = ss;
  __syncthreads();
  ss = sbuf[0] + sbuf[1] + sbuf[2] + sbuf[3];
  const float inv = 1.f / (sqrtf(ss * (1.f / 1023.f)) + 1e-8f);
  float4 o;
  o.x = d0 * inv; o.y = d1 * inv; o.z = d2 * inv; o.w = d3 * inv;
  *(float4*)(out + base) = o;
}

// ---------------- host orchestration --------------------------------------
extern "C" void kernel_launch(void* const* d_in, const int* in_sizes, int n_in,
                              void* d_out, int out_size, void* d_ws, size_t ws_size,
                              hipStream_t stream) {
  (void)in_sizes; (void)n_in; (void)out_size; (void)ws_size;
  const float* queries = (const float*)d_in[0];
  const float* keys    = (const float*)d_in[1];
  const float* values  = (const float*)d_in[2];
  const float* Wq = (const float*)d_in[3];  const float* bq = (const float*)d_in[4];
  const float* Wk = (const float*)d_in[5];  const float* bk = (const float*)d_in[6];
  const float* Wv = (const float*)d_in[7];  const float* bv = (const float*)d_in[8];
  const float* Wo = (const float*)d_in[9];  const float* bo = (const float*)d_in[10];
  float* out = (float*)d_out;

  char* w = (char*)d_ws;
  const size_t SZ_X = (size_t)4096 * 1024 * 2;   // 8 MB (bf16 [4096,1024])
  const size_t SZ_W = (size_t)1024 * 1024 * 2;   // 2 MB
  short* Xq  = (short*)w; w += SZ_X;
  short* Xk  = (short*)w; w += SZ_X;
  short* Xv  = (short*)w; w += SZ_X;
  short* Wtq = (short*)w; w += SZ_W;
  short* Wtk = (short*)w; w += SZ_W;
  short* Wtv = (short*)w; w += SZ_W;
  short* Wto = (short*)w; w += SZ_W;
  short* Qb  = (short*)w; w += SZ_X;
  short* Kb  = (short*)w; w += SZ_X;
  short* Vtb = (short*)w; w += SZ_X;
  short* Ab  = (short*)w; w += SZ_X;
  unsigned* kbits = (unsigned*)w; w += 4096;
  float* proj = (float*)w; w += (size_t)4096 * 1024 * 4;

  cvt3_kernel<<<12288, 256, 0, stream>>>(queries, keys, values, Xq, Xk, Xv);
  wt_kernel<<<dim3(16, 16, 4), 256, 0, stream>>>(Wq, Wk, Wv, Wo, Wtq, Wtk, Wtv, Wto);
  qkv_gemm<<<dim3(8, 32, 3), 256, 0, stream>>>(Xq, Xk, Xv, Wtq, Wtk, Wtv,
                                               bq, bk, bv, Qb, Kb, Vtb);
  key_mask_kernel<<<128, 256, 0, stream>>>(Kb, kbits);
  attn_kernel<<<1024, 128, 0, stream>>>(Qb, Kb, Vtb, kbits, Ab);
  out_gemm<<<dim3(8, 32), 256, 0, stream>>>(Ab, Wto, bo, proj);
  ln_kernel<<<4096, 256, 0, stream>>>(queries, proj, out);
}